// Round 10
// baseline (1140.870 us; speedup 1.0000x reference)
//
#include <hip/hip_runtime.h>
#include <math.h>

#define NN 100000
#define EE 1600000
#define ETOT 1700000
#define MM 20000
#define GG 512

#define NBUCK 782   // ceil(100000/128)
#define NB1 256     // phase-1 blocks (must match k_bscan_a's 256 threads)
#define CAP 4096    // max edges per bucket held in LDS (expected 2174 +- 47)

static constexpr int NB_N256 = (NN + 255) / 256;      // 391
static constexpr int NB_E256 = (ETOT + 255) / 256;    // 6641
static constexpr int NB_AGG  = NN / 32;               // 3125 (exact: 100000/32)

// small-buffer layout (float indices)
#define SM_MEAN 0
#define SM_WEA 16
#define SM_VS4 272
#define SM_VD4 400
#define SM_SELF 528   // 4 x u64 self-loop logit packs (8 floats)
#define SM_W4P 536
#define SM_TOTAL 8728

typedef unsigned long long ull;

__device__ __forceinline__ unsigned short f2bf(float f) {
  unsigned int u = __float_as_uint(f);
  u += 0x7fffu + ((u >> 16) & 1u);
  return (unsigned short)(u >> 16);
}
__device__ __forceinline__ float bf2f(unsigned int h) {
  return __uint_as_float(h << 16);
}
__device__ __forceinline__ float lrelu(float v, float s) { return v > 0.f ? v : s * v; }

// ---- precompute reduced weights ----
__global__ __launch_bounds__(256) void k_pre(
    float* __restrict__ sm, const float* __restrict__ We1, const float* __restrict__ We2,
    const float* __restrict__ We3, const float* __restrict__ We4,
    const float* __restrict__ ae1, const float* __restrict__ ae2,
    const float* __restrict__ ae3, const float* __restrict__ ae4,
    const float* __restrict__ as4, const float* __restrict__ ad4,
    const float* __restrict__ W4) {
  int t = threadIdx.x;
  {
    int l = t >> 6, d = (t >> 2) & 15, h = t & 3;
    const float* We = (l == 0) ? We1 : (l == 1) ? We2 : (l == 2) ? We3 : We4;
    const float* ae = (l == 0) ? ae1 : (l == 1) ? ae2 : (l == 2) ? ae3 : ae4;
    int C = (l == 3) ? 64 : 8;
    float s = 0.f;
    for (int c = 0; c < C; c++) s += We[d * (4 * C) + h * C + c] * ae[h * C + c];
    sm[SM_WEA + l * 64 + d * 4 + h] = s;
  }
  if (t < 128) {
    int k = t >> 2, h = t & 3;
    float s1 = 0.f, s2 = 0.f;
    for (int c = 0; c < 64; c++) {
      float w = W4[k * 256 + h * 64 + c];
      s1 += w * as4[h * 64 + c];
      s2 += w * ad4[h * 64 + c];
    }
    sm[SM_VS4 + t] = s1;
    sm[SM_VD4 + t] = s2;
  }
  for (int i = t; i < 8192; i += 256) {
    int row = i >> 6, c = i & 63;
    int h = row >> 5, k = row & 31;
    sm[SM_W4P + i] = 0.25f * W4[k * 256 + h * 64 + c];
  }
}

// ---- sort phase 1: per-block bucket histogram (ei only) ----
__global__ __launch_bounds__(1024) void k_hist1(const int* __restrict__ ei,
                                                int* __restrict__ blk_cnt) {
  __shared__ int hist[NBUCK];
  int t = threadIdx.x;
  for (int i = t; i < NBUCK; i += 1024) hist[i] = 0;
  __syncthreads();
  for (int e = blockIdx.x * 1024 + t; e < ETOT; e += NB1 * 1024) {
    int dst = (e < EE) ? ei[EE + e] : (e - EE);
    atomicAdd(&hist[dst >> 7], 1);
  }
  __syncthreads();
  for (int i = t; i < NBUCK; i += 1024) blk_cnt[blockIdx.x * NBUCK + i] = hist[i];
}

// ---- scan A: per-bucket exclusive scan over the 256 blocks ----
__global__ __launch_bounds__(256) void k_bscan_a(const int* __restrict__ blk_cnt,
                                                 int* __restrict__ blk_base_T,
                                                 int* __restrict__ bucket_tot) {
  __shared__ int s[256];
  int b = blockIdx.x, t = threadIdx.x;
  int v = blk_cnt[t * NBUCK + b];
  s[t] = v;
  __syncthreads();
  for (int off = 1; off < 256; off <<= 1) {
    int x = (t >= off) ? s[t - off] : 0;
    __syncthreads();
    s[t] += x;
    __syncthreads();
  }
  blk_base_T[b * 256 + t] = s[t] - v;
  if (t == 255) bucket_tot[b] = s[255];
}

// ---- scan B: exclusive scan of bucket totals ----
__global__ __launch_bounds__(1024) void k_bscan_b(const int* __restrict__ bucket_tot,
                                                  int* __restrict__ bucket_base,
                                                  int* __restrict__ row_off) {
  __shared__ int s[1024];
  int t = threadIdx.x;
  int v = (t < NBUCK) ? bucket_tot[t] : 0;
  s[t] = v;
  __syncthreads();
  for (int off = 1; off < 1024; off <<= 1) {
    int x = (t >= off) ? s[t - off] : 0;
    __syncthreads();
    s[t] += x;
    __syncthreads();
  }
  if (t < NBUCK) bucket_base[t] = s[t] - v;
  if (t == 0) {
    bucket_base[NBUCK] = ETOT;
    row_off[NN] = ETOT;
  }
}

// ---- sort phase 1 scatter: packed (src, eid|dstlow) into dense bucket regions ----
__global__ __launch_bounds__(1024) void k_scatter1(const int* __restrict__ ei,
                                                   const int* __restrict__ bucket_base,
                                                   const int* __restrict__ blk_base_T,
                                                   uint2* __restrict__ pairs) {
  __shared__ int base[NBUCK];
  __shared__ int rank[NBUCK];
  int t = threadIdx.x, blk = blockIdx.x;
  for (int i = t; i < NBUCK; i += 1024) {
    base[i] = bucket_base[i] + blk_base_T[i * 256 + blk];
    rank[i] = 0;
  }
  __syncthreads();
  for (int e = blk * 1024 + t; e < ETOT; e += NB1 * 1024) {
    int src, dst;
    if (e < EE) {
      src = ei[e];
      dst = ei[EE + e];
    } else {
      src = dst = e - EE;
    }
    int bin = dst >> 7;
    int r = atomicAdd(&rank[bin], 1);
    pairs[base[bin] + r] =
        make_uint2((unsigned)src, (unsigned)e | ((unsigned)(dst & 127) << 21));
  }
}

// ---- sort phase 2 (lean): LDS exact sort, coalesced csr_src + eidx writes,
//      records per-node self-loop CSR position ----
__global__ __launch_bounds__(256) void k_sort2(const uint2* __restrict__ pairs,
                                               const int* __restrict__ bucket_base,
                                               int* __restrict__ row_off,
                                               int* __restrict__ csr_src,
                                               int* __restrict__ eidx,
                                               int* __restrict__ selfpos) {
  __shared__ uint2 plds[CAP];
  __shared__ unsigned short perm[CAP];
  __shared__ int hist[128];
  __shared__ int scan[128];
  __shared__ int rankv[128];
  int b = blockIdx.x, t = threadIdx.x;
  int start = bucket_base[b], end = bucket_base[b + 1];
  int cnt = end - start;
  if (t < 128) hist[t] = 0;
  __syncthreads();
  bool fits = (cnt <= CAP);
  if (fits) {
    for (int i = t; i < cnt; i += 256) {
      uint2 pe = pairs[start + i];
      plds[i] = pe;
      atomicAdd(&hist[(pe.y >> 21) & 127], 1);
    }
  } else {
    for (int i = t; i < cnt; i += 256)
      atomicAdd(&hist[(pairs[start + i].y >> 21) & 127], 1);
  }
  __syncthreads();
  if (t < 128) scan[t] = hist[t];
  __syncthreads();
  for (int off = 1; off < 128; off <<= 1) {
    int x = (t >= off && t < 128) ? scan[t - off] : 0;
    __syncthreads();
    if (t < 128) scan[t] += x;
    __syncthreads();
  }
  if (t < 128) {
    int excl = scan[t] - hist[t];
    rankv[t] = excl;
    int dst = b * 128 + t;
    if (dst < NN) row_off[dst] = start + excl;
  }
  __syncthreads();
  if (fits) {
    for (int i = t; i < cnt; i += 256) {
      int bin = (plds[i].y >> 21) & 127;
      int r = atomicAdd(&rankv[bin], 1);
      perm[r] = (unsigned short)i;
    }
    __syncthreads();
    for (int r = t; r < cnt; r += 256) {
      uint2 pe = plds[perm[r]];
      unsigned eid = pe.y & 0x1fffffu;
      csr_src[start + r] = (int)pe.x;
      eidx[start + r] = (int)eid;
      if (eid >= EE) selfpos[b * 128 + ((pe.y >> 21) & 127)] = start + r;
    }
  } else {
    for (int i = t; i < cnt; i += 256) {
      uint2 pe = pairs[start + i];
      int bin = (pe.y >> 21) & 127;
      unsigned eid = pe.y & 0x1fffffu;
      int r = atomicAdd(&rankv[bin], 1);
      csr_src[start + r] = (int)pe.x;
      eidx[start + r] = (int)eid;
      if (eid >= EE) selfpos[b * 128 + bin] = start + r;
    }
  }
}

// ---- pack GEMV in CSR order (real edges only) + fused ea column-sum ----
__global__ __launch_bounds__(256) void k_pack(const int* __restrict__ eidx,
                                              const float* __restrict__ ea,
                                              float* __restrict__ sm,
                                              ull* __restrict__ apc) {
  __shared__ float sWea[256];
  __shared__ float lsum[16];
  int t = threadIdx.x;
  sWea[t] = sm[SM_WEA + t];
  if (t < 16) lsum[t] = 0.f;
  __syncthreads();
  int pos = blockIdx.x * 256 + t;
  float eav[16];
#pragma unroll
  for (int d = 0; d < 16; d++) eav[d] = 0.f;
  bool real = false;
  if (pos < ETOT) {
    int eid = eidx[pos];
    if (eid < EE) {
      real = true;
      const float4* p = (const float4*)(ea + (size_t)eid * 16);
      float4 v0 = p[0], v1 = p[1], v2 = p[2], v3 = p[3];
      eav[0] = v0.x; eav[1] = v0.y; eav[2] = v0.z; eav[3] = v0.w;
      eav[4] = v1.x; eav[5] = v1.y; eav[6] = v1.z; eav[7] = v1.w;
      eav[8] = v2.x; eav[9] = v2.y; eav[10] = v2.z; eav[11] = v2.w;
      eav[12] = v3.x; eav[13] = v3.y; eav[14] = v3.z; eav[15] = v3.w;
    }
  }
  if (real) {
#pragma unroll
    for (int l = 0; l < 4; l++) {
      ull pk = 0;
#pragma unroll
      for (int h = 0; h < 4; h++) {
        float s = 0.f;
#pragma unroll
        for (int d = 0; d < 16; d++) s += eav[d] * sWea[l * 64 + d * 4 + h];
        pk |= (ull)f2bf(s) << (16 * h);
      }
      apc[(size_t)l * ETOT + pos] = pk;
    }
  }
  // wave butterfly reduce the 16 dim-sums (self/inactive lanes contribute 0)
#pragma unroll
  for (int d = 0; d < 16; d++) {
    float v = eav[d];
    for (int m = 1; m < 64; m <<= 1) v += __shfl_xor(v, m, 64);
    eav[d] = v;
  }
  if ((t & 63) == 0) {
#pragma unroll
    for (int d = 0; d < 16; d++) atomicAdd(&lsum[d], eav[d]);
  }
  __syncthreads();
  if (t < 16) atomicAdd(&sm[SM_MEAN + t], lsum[t]);
}

// ---- finalize mean, compute shared self-loop pack per layer ----
__global__ __launch_bounds__(64) void k_selfpack(float* __restrict__ sm) {
  int t = threadIdx.x;
  if (t < 16) sm[SM_MEAN + t] *= (1.f / EE);
  __syncthreads();
  if (t < 4) {
    ull pk = 0;
    for (int h = 0; h < 4; h++) {
      float s = 0.f;
      for (int d = 0; d < 16; d++) s += sm[SM_MEAN + d] * sm[SM_WEA + t * 64 + d * 4 + h];
      pk |= (ull)f2bf(s) << (16 * h);
    }
    ((ull*)(sm + SM_SELF))[t] = pk;
  }
}

// ---- patch self-loop pack slots (apc lines L3-resident from k_pack) ----
__global__ __launch_bounds__(256) void k_selffix(const int* __restrict__ selfpos,
                                                 const float* __restrict__ sm,
                                                 ull* __restrict__ apc) {
  int n = blockIdx.x * 256 + threadIdx.x;
  if (n >= NN) return;
  int pos = selfpos[n];
  const ull* sp = (const ull*)(sm + SM_SELF);
  ull p0 = sp[0], p1 = sp[1], p2 = sp[2], p3 = sp[3];
  apc[pos] = p0;
  apc[(size_t)ETOT + pos] = p1;
  apc[2 * (size_t)ETOT + pos] = p2;
  apc[3 * (size_t)ETOT + pos] = p3;
}

// ---- mark dvi target nodes ----
__global__ __launch_bounds__(256) void k_mark(const int* __restrict__ dvi,
                                              char* __restrict__ mark) {
  int i = blockIdx.x * 256 + threadIdx.x;
  if (i < GG) mark[dvi[i]] = 1;
}

// ---- layer-1 node transform: hx = x@W1 (bf16 out), alpha reductions ----
template <int DIN>
__global__ __launch_bounds__(256) void k_t(const float* __restrict__ in,
                                           const float* __restrict__ W,
                                           const float* __restrict__ a_s,
                                           const float* __restrict__ a_d,
                                           unsigned short* __restrict__ hxb,
                                           float* __restrict__ ssrc,
                                           float* __restrict__ sdst) {
  __shared__ float4 sW[DIN * 8];
  __shared__ float sas[32], sad[32];
  int t = threadIdx.x;
  for (int i = t; i < DIN * 8; i += 256) sW[i] = ((const float4*)W)[i];
  if (t < 32) { sas[t] = a_s[t]; sad[t] = a_d[t]; }
  __syncthreads();
  int n = blockIdx.x * 256 + t;
  if (n >= NN) return;
  float acc[32];
#pragma unroll
  for (int j = 0; j < 32; j++) acc[j] = 0.f;
  const float* xr = in + (size_t)n * DIN;
  for (int k = 0; k < DIN; k += 4) {
    float4 xv = *(const float4*)(xr + k);
    float xa[4] = {xv.x, xv.y, xv.z, xv.w};
#pragma unroll
    for (int kk = 0; kk < 4; kk++) {
#pragma unroll
      for (int j4 = 0; j4 < 8; j4++) {
        float4 ww = sW[(k + kk) * 8 + j4];
        acc[j4 * 4 + 0] += xa[kk] * ww.x;
        acc[j4 * 4 + 1] += xa[kk] * ww.y;
        acc[j4 * 4 + 2] += xa[kk] * ww.z;
        acc[j4 * 4 + 3] += xa[kk] * ww.w;
      }
    }
  }
  float ssum[4], dsum[4];
#pragma unroll
  for (int h = 0; h < 4; h++) {
    float s = 0.f, d = 0.f;
#pragma unroll
    for (int c = 0; c < 8; c++) {
      s += acc[h * 8 + c] * sas[h * 8 + c];
      d += acc[h * 8 + c] * sad[h * 8 + c];
    }
    ssum[h] = s;
    dsum[h] = d;
  }
  unsigned int up[16];
#pragma unroll
  for (int i = 0; i < 16; i++)
    up[i] = (unsigned)f2bf(acc[2 * i]) | ((unsigned)f2bf(acc[2 * i + 1]) << 16);
  uint4* ho = (uint4*)(hxb + (size_t)n * 32);
  ho[0] = make_uint4(up[0], up[1], up[2], up[3]);
  ho[1] = make_uint4(up[4], up[5], up[6], up[7]);
  ho[2] = make_uint4(up[8], up[9], up[10], up[11]);
  ho[3] = make_uint4(up[12], up[13], up[14], up[15]);
  ((float4*)ssrc)[n] = make_float4(ssum[0], ssum[1], ssum[2], ssum[3]);
  ((float4*)sdst)[n] = make_float4(dsum[0], dsum[1], dsum[2], dsum[3]);
}

// ---- fused aggregation (layers 1,2): agg + bias + lrelu + in-register 32x32
//      transform via shfl + next-layer alpha reductions + bf16 feature write ----
__global__ __launch_bounds__(256) void k_aggt(const int* __restrict__ row_off,
                                              const int* __restrict__ csr_src,
                                              const ull* __restrict__ apl,
                                              const unsigned short* __restrict__ hxb,
                                              const float* __restrict__ ssrc,
                                              const float* __restrict__ sdst,
                                              const float* __restrict__ bias,
                                              const float* __restrict__ Wn,
                                              const float* __restrict__ asn,
                                              const float* __restrict__ adn,
                                              unsigned short* __restrict__ hxb_out,
                                              float* __restrict__ ssrc_out,
                                              float* __restrict__ sdst_out) {
  __shared__ float4 sW[256];  // Wn [32][32] as float4
  __shared__ float sas[32], sad[32];
  int t = threadIdx.x;
  sW[t] = ((const float4*)Wn)[t];
  if (t < 32) { sas[t] = asn[t]; sad[t] = adn[t]; }
  __syncthreads();
  int g = t >> 3, j = t & 7, h = j >> 1;
  int n = blockIdx.x * 32 + g;
  float sd = sdst[n * 4 + h];
  int e0 = row_off[n], e1 = row_off[n + 1];
  float den = 0.f;
  float4 acc = make_float4(0.f, 0.f, 0.f, 0.f);
  int e = e0;
  for (; e + 8 <= e1; e += 8) {
    int s[8];
    ull p[8];
#pragma unroll
    for (int k = 0; k < 8; k++) s[k] = csr_src[e + k];
#pragma unroll
    for (int k = 0; k < 8; k++) p[k] = apl[e + k];
    float a[8];
    uint2 u[8];
#pragma unroll
    for (int k = 0; k < 8; k++) a[k] = ssrc[s[k] * 4 + h];
#pragma unroll
    for (int k = 0; k < 8; k++)
      u[k] = *(const uint2*)(hxb + (size_t)s[k] * 32 + (j << 2));
#pragma unroll
    for (int k = 0; k < 8; k++) {
      float al = a[k] + sd + bf2f((unsigned)(unsigned short)(p[k] >> (16 * h)));
      float q = __expf(fminf(lrelu(al, 0.2f), 80.f));
      den += q;
      acc.x += q * bf2f(u[k].x & 0xffffu);
      acc.y += q * bf2f(u[k].x >> 16);
      acc.z += q * bf2f(u[k].y & 0xffffu);
      acc.w += q * bf2f(u[k].y >> 16);
    }
  }
  for (; e + 4 <= e1; e += 4) {
    int s[4];
    ull p[4];
#pragma unroll
    for (int k = 0; k < 4; k++) s[k] = csr_src[e + k];
#pragma unroll
    for (int k = 0; k < 4; k++) p[k] = apl[e + k];
    float a[4];
    uint2 u[4];
#pragma unroll
    for (int k = 0; k < 4; k++) a[k] = ssrc[s[k] * 4 + h];
#pragma unroll
    for (int k = 0; k < 4; k++)
      u[k] = *(const uint2*)(hxb + (size_t)s[k] * 32 + (j << 2));
#pragma unroll
    for (int k = 0; k < 4; k++) {
      float al = a[k] + sd + bf2f((unsigned)(unsigned short)(p[k] >> (16 * h)));
      float q = __expf(fminf(lrelu(al, 0.2f), 80.f));
      den += q;
      acc.x += q * bf2f(u[k].x & 0xffffu);
      acc.y += q * bf2f(u[k].x >> 16);
      acc.z += q * bf2f(u[k].y & 0xffffu);
      acc.w += q * bf2f(u[k].y >> 16);
    }
  }
  for (; e < e1; ++e) {
    int src = csr_src[e];
    ull pk = apl[e];
    float al = ssrc[src * 4 + h] + sd + bf2f((unsigned)(unsigned short)(pk >> (16 * h)));
    al = fminf(lrelu(al, 0.2f), 80.f);
    uint2 u = *(const uint2*)(hxb + (size_t)src * 32 + (j << 2));
    float p = __expf(al);
    den += p;
    acc.x += p * bf2f(u.x & 0xffffu);
    acc.y += p * bf2f(u.x >> 16);
    acc.z += p * bf2f(u.y & 0xffffu);
    acc.w += p * bf2f(u.y >> 16);
  }
  float inv = 1.f / (den + 1e-16f);
  float4 b = *(const float4*)(bias + (j << 2));
  float i0 = lrelu(acc.x * inv + b.x, 0.01f);
  float i1 = lrelu(acc.y * inv + b.y, 0.01f);
  float i2 = lrelu(acc.z * inv + b.z, 0.01f);
  float i3 = lrelu(acc.w * inv + b.w, 0.01f);
  // in-register transform: next_hx[j*4..+3] = sum_i in[i] * Wn[i][j*4..+3]
  int gbase = (t & 63) & ~7;
  float n0 = 0.f, n1 = 0.f, n2 = 0.f, n3 = 0.f;
#pragma unroll
  for (int k = 0; k < 8; k++) {
    int sl = gbase + k;
    float v0 = __shfl(i0, sl, 64);
    float v1 = __shfl(i1, sl, 64);
    float v2 = __shfl(i2, sl, 64);
    float v3 = __shfl(i3, sl, 64);
    float4 w0 = sW[(k * 4 + 0) * 8 + j];
    n0 += v0 * w0.x; n1 += v0 * w0.y; n2 += v0 * w0.z; n3 += v0 * w0.w;
    float4 w1 = sW[(k * 4 + 1) * 8 + j];
    n0 += v1 * w1.x; n1 += v1 * w1.y; n2 += v1 * w1.z; n3 += v1 * w1.w;
    float4 w2 = sW[(k * 4 + 2) * 8 + j];
    n0 += v2 * w2.x; n1 += v2 * w2.y; n2 += v2 * w2.z; n3 += v2 * w2.w;
    float4 w3 = sW[(k * 4 + 3) * 8 + j];
    n0 += v3 * w3.x; n1 += v3 * w3.y; n2 += v3 * w3.z; n3 += v3 * w3.w;
  }
  // next-layer attention reductions: lane's 4 dims all in head j>>1
  float ps = n0 * sas[j * 4 + 0] + n1 * sas[j * 4 + 1] + n2 * sas[j * 4 + 2] +
             n3 * sas[j * 4 + 3];
  float pd = n0 * sad[j * 4 + 0] + n1 * sad[j * 4 + 1] + n2 * sad[j * 4 + 2] +
             n3 * sad[j * 4 + 3];
  ps += __shfl_xor(ps, 1, 64);
  pd += __shfl_xor(pd, 1, 64);
  if ((j & 1) == 0) {
    ssrc_out[n * 4 + (j >> 1)] = ps;
    sdst_out[n * 4 + (j >> 1)] = pd;
  }
  unsigned u0 = (unsigned)f2bf(n0) | ((unsigned)f2bf(n1) << 16);
  unsigned u1 = (unsigned)f2bf(n2) | ((unsigned)f2bf(n3) << 16);
  *(uint2*)(hxb_out + (size_t)n * 32 + (j << 2)) = make_uint2(u0, u1);
}

// ---- fused aggregation (layer 3): agg + bias + lrelu + Vs4/Vd4 reductions
//      + bf16 h3 write ----
__global__ __launch_bounds__(256) void k_aggt3(const int* __restrict__ row_off,
                                               const int* __restrict__ csr_src,
                                               const ull* __restrict__ apl,
                                               const unsigned short* __restrict__ hxb,
                                               const float* __restrict__ ssrc,
                                               const float* __restrict__ sdst,
                                               const float* __restrict__ bias,
                                               const float* __restrict__ sm,
                                               unsigned short* __restrict__ h3b,
                                               float* __restrict__ ssrc4,
                                               float* __restrict__ sdst4) {
  __shared__ float sVs[128], sVd[128];
  int t = threadIdx.x;
  if (t < 128) { sVs[t] = sm[SM_VS4 + t]; sVd[t] = sm[SM_VD4 + t]; }
  __syncthreads();
  int g = t >> 3, j = t & 7, h = j >> 1;
  int n = blockIdx.x * 32 + g;
  float sd = sdst[n * 4 + h];
  int e0 = row_off[n], e1 = row_off[n + 1];
  float den = 0.f;
  float4 acc = make_float4(0.f, 0.f, 0.f, 0.f);
  int e = e0;
  for (; e + 8 <= e1; e += 8) {
    int s[8];
    ull p[8];
#pragma unroll
    for (int k = 0; k < 8; k++) s[k] = csr_src[e + k];
#pragma unroll
    for (int k = 0; k < 8; k++) p[k] = apl[e + k];
    float a[8];
    uint2 u[8];
#pragma unroll
    for (int k = 0; k < 8; k++) a[k] = ssrc[s[k] * 4 + h];
#pragma unroll
    for (int k = 0; k < 8; k++)
      u[k] = *(const uint2*)(hxb + (size_t)s[k] * 32 + (j << 2));
#pragma unroll
    for (int k = 0; k < 8; k++) {
      float al = a[k] + sd + bf2f((unsigned)(unsigned short)(p[k] >> (16 * h)));
      float q = __expf(fminf(lrelu(al, 0.2f), 80.f));
      den += q;
      acc.x += q * bf2f(u[k].x & 0xffffu);
      acc.y += q * bf2f(u[k].x >> 16);
      acc.z += q * bf2f(u[k].y & 0xffffu);
      acc.w += q * bf2f(u[k].y >> 16);
    }
  }
  for (; e + 4 <= e1; e += 4) {
    int s[4];
    ull p[4];
#pragma unroll
    for (int k = 0; k < 4; k++) s[k] = csr_src[e + k];
#pragma unroll
    for (int k = 0; k < 4; k++) p[k] = apl[e + k];
    float a[4];
    uint2 u[4];
#pragma unroll
    for (int k = 0; k < 4; k++) a[k] = ssrc[s[k] * 4 + h];
#pragma unroll
    for (int k = 0; k < 4; k++)
      u[k] = *(const uint2*)(hxb + (size_t)s[k] * 32 + (j << 2));
#pragma unroll
    for (int k = 0; k < 4; k++) {
      float al = a[k] + sd + bf2f((unsigned)(unsigned short)(p[k] >> (16 * h)));
      float q = __expf(fminf(lrelu(al, 0.2f), 80.f));
      den += q;
      acc.x += q * bf2f(u[k].x & 0xffffu);
      acc.y += q * bf2f(u[k].x >> 16);
      acc.z += q * bf2f(u[k].y & 0xffffu);
      acc.w += q * bf2f(u[k].y >> 16);
    }
  }
  for (; e < e1; ++e) {
    int src = csr_src[e];
    ull pk = apl[e];
    float al = ssrc[src * 4 + h] + sd + bf2f((unsigned)(unsigned short)(pk >> (16 * h)));
    al = fminf(lrelu(al, 0.2f), 80.f);
    uint2 u = *(const uint2*)(hxb + (size_t)src * 32 + (j << 2));
    float p = __expf(al);
    den += p;
    acc.x += p * bf2f(u.x & 0xffffu);
    acc.y += p * bf2f(u.x >> 16);
    acc.z += p * bf2f(u.y & 0xffffu);
    acc.w += p * bf2f(u.y >> 16);
  }
  float inv = 1.f / (den + 1e-16f);
  float4 b = *(const float4*)(bias + (j << 2));
  float o0 = lrelu(acc.x * inv + b.x, 0.01f);
  float o1 = lrelu(acc.y * inv + b.y, 0.01f);
  float o2 = lrelu(acc.z * inv + b.z, 0.01f);
  float o3 = lrelu(acc.w * inv + b.w, 0.01f);
  // Vs4/Vd4 reductions: ssum4[hh] = sum_k h3[k] * Vs4[k][hh]
  float ps0 = o0 * sVs[(j * 4 + 0) * 4 + 0] + o1 * sVs[(j * 4 + 1) * 4 + 0] +
              o2 * sVs[(j * 4 + 2) * 4 + 0] + o3 * sVs[(j * 4 + 3) * 4 + 0];
  float ps1 = o0 * sVs[(j * 4 + 0) * 4 + 1] + o1 * sVs[(j * 4 + 1) * 4 + 1] +
              o2 * sVs[(j * 4 + 2) * 4 + 1] + o3 * sVs[(j * 4 + 3) * 4 + 1];
  float ps2 = o0 * sVs[(j * 4 + 0) * 4 + 2] + o1 * sVs[(j * 4 + 1) * 4 + 2] +
              o2 * sVs[(j * 4 + 2) * 4 + 2] + o3 * sVs[(j * 4 + 3) * 4 + 2];
  float ps3 = o0 * sVs[(j * 4 + 0) * 4 + 3] + o1 * sVs[(j * 4 + 1) * 4 + 3] +
              o2 * sVs[(j * 4 + 2) * 4 + 3] + o3 * sVs[(j * 4 + 3) * 4 + 3];
  float pd0 = o0 * sVd[(j * 4 + 0) * 4 + 0] + o1 * sVd[(j * 4 + 1) * 4 + 0] +
              o2 * sVd[(j * 4 + 2) * 4 + 0] + o3 * sVd[(j * 4 + 3) * 4 + 0];
  float pd1 = o0 * sVd[(j * 4 + 0) * 4 + 1] + o1 * sVd[(j * 4 + 1) * 4 + 1] +
              o2 * sVd[(j * 4 + 2) * 4 + 1] + o3 * sVd[(j * 4 + 3) * 4 + 1];
  float pd2 = o0 * sVd[(j * 4 + 0) * 4 + 2] + o1 * sVd[(j * 4 + 1) * 4 + 2] +
              o2 * sVd[(j * 4 + 2) * 4 + 2] + o3 * sVd[(j * 4 + 3) * 4 + 2];
  float pd3 = o0 * sVd[(j * 4 + 0) * 4 + 3] + o1 * sVd[(j * 4 + 1) * 4 + 3] +
              o2 * sVd[(j * 4 + 2) * 4 + 3] + o3 * sVd[(j * 4 + 3) * 4 + 3];
#pragma unroll
  for (int m = 1; m < 8; m <<= 1) {
    ps0 += __shfl_xor(ps0, m, 64);
    ps1 += __shfl_xor(ps1, m, 64);
    ps2 += __shfl_xor(ps2, m, 64);
    ps3 += __shfl_xor(ps3, m, 64);
    pd0 += __shfl_xor(pd0, m, 64);
    pd1 += __shfl_xor(pd1, m, 64);
    pd2 += __shfl_xor(pd2, m, 64);
    pd3 += __shfl_xor(pd3, m, 64);
  }
  if (j == 0) {
    ((float4*)ssrc4)[n] = make_float4(ps0, ps1, ps2, ps3);
    ((float4*)sdst4)[n] = make_float4(pd0, pd1, pd2, pd3);
  }
  unsigned u0 = (unsigned)f2bf(o0) | ((unsigned)f2bf(o1) << 16);
  unsigned u1 = (unsigned)f2bf(o2) | ((unsigned)f2bf(o3) << 16);
  *(uint2*)(h3b + (size_t)n * 32 + (j << 2)) = make_uint2(u0, u1);
}

// ---- layer-4 aggregation: aggregate h3 per head, no-max softmax, 4x batched ----
__global__ __launch_bounds__(256) void k_agg4(const int* __restrict__ row_off,
                                              const int* __restrict__ csr_src,
                                              const ull* __restrict__ apl,
                                              const unsigned short* __restrict__ h3b,
                                              const float* __restrict__ ssrc,
                                              const float* __restrict__ sdst,
                                              unsigned short* __restrict__ aggb) {
  int t = threadIdx.x;
  int g = t >> 3, j = t & 7;
  int n = blockIdx.x * 32 + g;
  if (n >= NN) return;
  float4 sdv = ((const float4*)sdst)[n];
  float sda[4] = {sdv.x, sdv.y, sdv.z, sdv.w};
  int e0 = row_off[n], e1 = row_off[n + 1];
  float den[4];
  float4 acc[4];
#pragma unroll
  for (int h = 0; h < 4; h++) {
    den[h] = 0.f;
    acc[h] = make_float4(0.f, 0.f, 0.f, 0.f);
  }
  int e = e0;
  for (; e + 4 <= e1; e += 4) {
    int s[4];
    ull p[4];
#pragma unroll
    for (int k = 0; k < 4; k++) s[k] = csr_src[e + k];
#pragma unroll
    for (int k = 0; k < 4; k++) p[k] = apl[e + k];
    float4 sv[4];
    uint2 u[4];
#pragma unroll
    for (int k = 0; k < 4; k++) sv[k] = ((const float4*)ssrc)[s[k]];
#pragma unroll
    for (int k = 0; k < 4; k++)
      u[k] = *(const uint2*)(h3b + (size_t)s[k] * 32 + (j << 2));
#pragma unroll
    for (int k = 0; k < 4; k++) {
      float x0 = bf2f(u[k].x & 0xffffu), x1 = bf2f(u[k].x >> 16);
      float x2 = bf2f(u[k].y & 0xffffu), x3 = bf2f(u[k].y >> 16);
      float sa[4] = {sv[k].x, sv[k].y, sv[k].z, sv[k].w};
#pragma unroll
      for (int h = 0; h < 4; h++) {
        float al = sa[h] + sda[h] + bf2f((unsigned)(unsigned short)(p[k] >> (16 * h)));
        float q = __expf(fminf(lrelu(al, 0.2f), 80.f));
        den[h] += q;
        acc[h].x += q * x0;
        acc[h].y += q * x1;
        acc[h].z += q * x2;
        acc[h].w += q * x3;
      }
    }
  }
  for (; e < e1; ++e) {
    int src = csr_src[e];
    ull pk = apl[e];
    float4 ssv = ((const float4*)ssrc)[src];
    float ssa[4] = {ssv.x, ssv.y, ssv.z, ssv.w};
    uint2 u = *(const uint2*)(h3b + (size_t)src * 32 + (j << 2));
    float hx0 = bf2f(u.x & 0xffffu), hx1 = bf2f(u.x >> 16);
    float hx2 = bf2f(u.y & 0xffffu), hx3 = bf2f(u.y >> 16);
#pragma unroll
    for (int h = 0; h < 4; h++) {
      float al = ssa[h] + sda[h] + bf2f((unsigned)(unsigned short)(pk >> (16 * h)));
      al = fminf(lrelu(al, 0.2f), 80.f);
      float p = __expf(al);
      den[h] += p;
      acc[h].x += p * hx0;
      acc[h].y += p * hx1;
      acc[h].z += p * hx2;
      acc[h].w += p * hx3;
    }
  }
#pragma unroll
  for (int h = 0; h < 4; h++) {
    float inv = 1.f / (den[h] + 1e-16f);
    unsigned int u0 = (unsigned)f2bf(acc[h].x * inv) | ((unsigned)f2bf(acc[h].y * inv) << 16);
    unsigned int u1 = (unsigned)f2bf(acc[h].z * inv) | ((unsigned)f2bf(acc[h].w * inv) << 16);
    *(uint2*)(aggb + (size_t)n * 128 + h * 32 + (j << 2)) = make_uint2(u0, u1);
  }
}

// ---- layer-4 epilogue + fused pool1 atomics + sparse h4 write ----
__global__ __launch_bounds__(256) void k_epi4p(const unsigned short* __restrict__ aggb,
                                               const float* __restrict__ sm,
                                               const float* __restrict__ b4,
                                               const int* __restrict__ sidx,
                                               const char* __restrict__ mark,
                                               float* __restrict__ pool1,
                                               float* __restrict__ h4) {
  __shared__ float4 sW[2048];
  __shared__ float sb[64];
  int t = threadIdx.x;
  for (int i = t; i < 2048; i += 256) sW[i] = ((const float4*)(sm + SM_W4P))[i];
  if (t < 64) sb[t] = b4[t];
  __syncthreads();
  int n = blockIdx.x * 256 + t;
  if (n >= NN) return;
  float acc[64];
#pragma unroll
  for (int j = 0; j < 64; j++) acc[j] = 0.f;
  const unsigned short* r = aggb + (size_t)n * 128;
  for (int k = 0; k < 128; k += 4) {
    uint2 u = *(const uint2*)(r + k);
    float va[4] = {bf2f(u.x & 0xffffu), bf2f(u.x >> 16), bf2f(u.y & 0xffffu),
                   bf2f(u.y >> 16)};
#pragma unroll
    for (int kk = 0; kk < 4; kk++) {
#pragma unroll
      for (int j4 = 0; j4 < 16; j4++) {
        float4 wv = sW[(k + kk) * 16 + j4];
        acc[j4 * 4 + 0] += va[kk] * wv.x;
        acc[j4 * 4 + 1] += va[kk] * wv.y;
        acc[j4 * 4 + 2] += va[kk] * wv.z;
        acc[j4 * 4 + 3] += va[kk] * wv.w;
      }
    }
  }
  float* prow = pool1 + (size_t)sidx[n] * 64;
  bool wr = mark[n] != 0;
  float* o = h4 + (size_t)n * 64;
#pragma unroll
  for (int j4 = 0; j4 < 16; j4++) {
    float4 ov;
    ov.x = lrelu(acc[j4 * 4 + 0] + sb[j4 * 4 + 0], 0.01f);
    ov.y = lrelu(acc[j4 * 4 + 1] + sb[j4 * 4 + 1], 0.01f);
    ov.z = lrelu(acc[j4 * 4 + 2] + sb[j4 * 4 + 2], 0.01f);
    ov.w = lrelu(acc[j4 * 4 + 3] + sb[j4 * 4 + 3], 0.01f);
    atomicAdd(&prow[j4 * 4 + 0], ov.x);
    atomicAdd(&prow[j4 * 4 + 1], ov.y);
    atomicAdd(&prow[j4 * 4 + 2], ov.z);
    atomicAdd(&prow[j4 * 4 + 3], ov.w);
    if (wr) ((float4*)o)[j4] = ov;
  }
}

// ---- pooling level 2 ----
__global__ __launch_bounds__(256) void k_pool2(const float* __restrict__ pool1,
                                               const float* __restrict__ snorm,
                                               const int* __restrict__ nodes,
                                               float* __restrict__ pool2) {
  int i = blockIdx.x * 256 + threadIdx.x;
  if (i >= MM * 64) return;
  int mi = i >> 6, c = i & 63;
  float v = pool1[i] / snorm[mi];
  atomicAdd(&pool2[(size_t)nodes[mi] * 64 + c], v);
}

// ---- final head: one wave per group ----
__global__ __launch_bounds__(64) void k_final(const float* __restrict__ pool2,
                                              const float* __restrict__ h4,
                                              const int* __restrict__ dvi,
                                              const float* __restrict__ Wp,
                                              const float* __restrict__ Wt,
                                              const float* __restrict__ Wo,
                                              const float* __restrict__ bo,
                                              float* __restrict__ out) {
  __shared__ float p[64], tt[64];
  int gI = blockIdx.x, j = threadIdx.x;
  p[j] = pool2[gI * 64 + j];
  tt[j] = h4[(size_t)dvi[gI] * 64 + j];
  __syncthreads();
  float f1 = 0.f, f2 = 0.f;
#pragma unroll 8
  for (int c = 0; c < 64; c++) {
    f1 += p[c] * Wp[c * 64 + j];
    f2 += tt[c] * Wt[c * 64 + j];
  }
  f1 = lrelu(f1, 0.01f);
  f2 = lrelu(f2, 0.01f);
  float v = f1 * Wo[j] + f2 * Wo[64 + j];
  for (int off = 32; off > 0; off >>= 1) v += __shfl_down(v, off, 64);
  if (j == 0) out[gI] = v + bo[0];
}

extern "C" void kernel_launch(void* const* d_in, const int* in_sizes, int n_in,
                              void* d_out, int out_size, void* d_ws, size_t ws_size,
                              hipStream_t stream) {
  const float* x = (const float*)d_in[0];
  const int* ei = (const int*)d_in[1];
  const float* ea = (const float*)d_in[2];
  const int* sidx = (const int*)d_in[3];
  const float* snorm = (const float*)d_in[4];
  const int* nodes = (const int*)d_in[5];
  const int* dvi = (const int*)d_in[6];
  const float* W1 = (const float*)d_in[7];
  const float* as1 = (const float*)d_in[9];
  const float* ad1 = (const float*)d_in[10];
  const float* b1 = (const float*)d_in[12];
  const float* W2 = (const float*)d_in[13];
  const float* as2 = (const float*)d_in[15];
  const float* ad2 = (const float*)d_in[16];
  const float* b2 = (const float*)d_in[18];
  const float* W3 = (const float*)d_in[19];
  const float* as3 = (const float*)d_in[21];
  const float* ad3 = (const float*)d_in[22];
  const float* b3 = (const float*)d_in[24];
  const float* b4 = (const float*)d_in[30];
  const float* Wp = (const float*)d_in[31];
  const float* Wt = (const float*)d_in[32];
  const float* Wo = (const float*)d_in[33];
  const float* bo = (const float*)d_in[34];
  float* out = (float*)d_out;

  char* w = (char*)d_ws;
  size_t off = 0;
  auto take = [&](size_t bytes) -> char* {
    char* p = w + off;
    off = (off + bytes + 255) & ~(size_t)255;
    return p;
  };
  int* row_off = (int*)take((size_t)(NN + 1) * 4);
  float* sm = (float*)take(SM_TOTAL * 4);
  uint2* pairs = (uint2*)take((size_t)ETOT * 8);
  int* csr_src = (int*)take((size_t)ETOT * 4);
  int* eidx = (int*)take((size_t)ETOT * 4);
  ull* apc = (ull*)take((size_t)ETOT * 4 * 8);
  int* blk_cnt = (int*)take((size_t)NB1 * NBUCK * 4);
  int* blk_base_T = (int*)take((size_t)NBUCK * NB1 * 4);
  int* bucket_tot = (int*)take((size_t)NBUCK * 4);
  int* bucket_base = (int*)take((size_t)(NBUCK + 1) * 4);
  int* selfpos = (int*)take((size_t)NN * 4);
  char* mark = (char*)take((size_t)NN);
  float* h4 = (float*)take((size_t)NN * 64 * 4);
  unsigned short* aggb = (unsigned short*)take((size_t)NN * 128 * 2);
  unsigned short* hxbA = (unsigned short*)take((size_t)NN * 32 * 2);
  unsigned short* hxbB = (unsigned short*)take((size_t)NN * 32 * 2);
  unsigned short* h3b = (unsigned short*)take((size_t)NN * 32 * 2);
  float* ssrcA = (float*)take((size_t)NN * 4 * 4);
  float* sdstA = (float*)take((size_t)NN * 4 * 4);
  float* ssrcB = (float*)take((size_t)NN * 4 * 4);
  float* sdstB = (float*)take((size_t)NN * 4 * 4);
  float* ssrc4 = (float*)take((size_t)NN * 4 * 4);
  float* sdst4 = (float*)take((size_t)NN * 4 * 4);
  float* pool1 = (float*)take((size_t)MM * 64 * 4);
  float* pool2 = (float*)take((size_t)GG * 64 * 4);
  if (off > ws_size) return;  // workspace too small -> visible validation failure

  hipMemsetAsync(sm, 0, 64, stream);
  hipMemsetAsync(mark, 0, (size_t)NN, stream);
  hipMemsetAsync(pool1, 0, (size_t)MM * 64 * 4, stream);
  hipMemsetAsync(pool2, 0, (size_t)GG * 64 * 4, stream);

  k_pre<<<1, 256, 0, stream>>>(sm, (const float*)d_in[8], (const float*)d_in[14],
                               (const float*)d_in[20], (const float*)d_in[26],
                               (const float*)d_in[11], (const float*)d_in[17],
                               (const float*)d_in[23], (const float*)d_in[29],
                               (const float*)d_in[27], (const float*)d_in[28],
                               (const float*)d_in[25]);
  k_mark<<<2, 256, 0, stream>>>(dvi, mark);

  // counting sort by dst (two-level, no global atomics)
  k_hist1<<<NB1, 1024, 0, stream>>>(ei, blk_cnt);
  k_bscan_a<<<NBUCK, 256, 0, stream>>>(blk_cnt, blk_base_T, bucket_tot);
  k_bscan_b<<<1, 1024, 0, stream>>>(bucket_tot, bucket_base, row_off);
  k_scatter1<<<NB1, 1024, 0, stream>>>(ei, bucket_base, blk_base_T, pairs);
  k_sort2<<<NBUCK, 256, 0, stream>>>(pairs, bucket_base, row_off, csr_src, eidx,
                                     selfpos);
  // pack GEMV (real edges) + fused ea-mean; then self-loop patch
  k_pack<<<NB_E256, 256, 0, stream>>>(eidx, ea, sm, apc);
  k_selfpack<<<1, 64, 0, stream>>>(sm);
  k_selffix<<<NB_N256, 256, 0, stream>>>(selfpos, sm, apc);

  // layer 1 transform, then fused agg+transform chain
  k_t<64><<<NB_N256, 256, 0, stream>>>(x, W1, as1, ad1, hxbA, ssrcA, sdstA);
  k_aggt<<<NB_AGG, 256, 0, stream>>>(row_off, csr_src, apc, hxbA, ssrcA, sdstA, b1, W2,
                                     as2, ad2, hxbB, ssrcB, sdstB);
  k_aggt<<<NB_AGG, 256, 0, stream>>>(row_off, csr_src, apc + (size_t)ETOT, hxbB, ssrcB,
                                     sdstB, b2, W3, as3, ad3, hxbA, ssrcA, sdstA);
  k_aggt3<<<NB_AGG, 256, 0, stream>>>(row_off, csr_src, apc + 2 * (size_t)ETOT, hxbA,
                                      ssrcA, sdstA, b3, sm, h3b, ssrc4, sdst4);
  k_agg4<<<NB_AGG, 256, 0, stream>>>(row_off, csr_src, apc + 3 * (size_t)ETOT, h3b,
                                     ssrc4, sdst4, aggb);
  k_epi4p<<<NB_N256, 256, 0, stream>>>(aggb, sm, b4, sidx, mark, pool1, h4);

  // pooling head
  k_pool2<<<(MM * 64) / 256, 256, 0, stream>>>(pool1, snorm, nodes, pool2);
  k_final<<<GG, 64, 0, stream>>>(pool2, h4, dvi, Wp, Wt, Wo, bo, out);
}

// Round 11
// 618.982 us; speedup vs baseline: 1.8431x; 1.8431x over previous
//
#include <hip/hip_runtime.h>
#include <math.h>

#define NN 100000
#define EE 1600000
#define ETOT 1700000
#define MM 20000
#define GG 512

#define NBUCK 782   // ceil(100000/128)
#define NB1 256     // phase-1 blocks (must match k_bscan_a's 256 threads)
#define CAP 4096    // max edges per bucket held in LDS (expected 2174 +- 47)

static constexpr int NB_N256 = (NN + 255) / 256;      // 391
static constexpr int NB_E256 = (ETOT + 255) / 256;    // 6641
static constexpr int NB_AGG  = NN / 32;               // 3125 (exact: 100000/32)

// small-buffer layout (float indices)
#define SM_MEAN 0
#define SM_WEA 16
#define SM_VS4 272
#define SM_VD4 400
#define SM_W4P 536
#define SM_TOTAL 8728

typedef unsigned long long ull;

__device__ __forceinline__ unsigned short f2bf(float f) {
  unsigned int u = __float_as_uint(f);
  u += 0x7fffu + ((u >> 16) & 1u);
  return (unsigned short)(u >> 16);
}
__device__ __forceinline__ float bf2f(unsigned int h) {
  return __uint_as_float(h << 16);
}
__device__ __forceinline__ float lrelu(float v, float s) { return v > 0.f ? v : s * v; }

// ---- precompute reduced weights ----
__global__ __launch_bounds__(256) void k_pre(
    float* __restrict__ sm, const float* __restrict__ We1, const float* __restrict__ We2,
    const float* __restrict__ We3, const float* __restrict__ We4,
    const float* __restrict__ ae1, const float* __restrict__ ae2,
    const float* __restrict__ ae3, const float* __restrict__ ae4,
    const float* __restrict__ as4, const float* __restrict__ ad4,
    const float* __restrict__ W4) {
  int t = threadIdx.x;
  {
    int l = t >> 6, d = (t >> 2) & 15, h = t & 3;
    const float* We = (l == 0) ? We1 : (l == 1) ? We2 : (l == 2) ? We3 : We4;
    const float* ae = (l == 0) ? ae1 : (l == 1) ? ae2 : (l == 2) ? ae3 : ae4;
    int C = (l == 3) ? 64 : 8;
    float s = 0.f;
    for (int c = 0; c < C; c++) s += We[d * (4 * C) + h * C + c] * ae[h * C + c];
    sm[SM_WEA + l * 64 + d * 4 + h] = s;
  }
  if (t < 128) {
    int k = t >> 2, h = t & 3;
    float s1 = 0.f, s2 = 0.f;
    for (int c = 0; c < 64; c++) {
      float w = W4[k * 256 + h * 64 + c];
      s1 += w * as4[h * 64 + c];
      s2 += w * ad4[h * 64 + c];
    }
    sm[SM_VS4 + t] = s1;
    sm[SM_VD4 + t] = s2;
  }
  for (int i = t; i < 8192; i += 256) {
    int row = i >> 6, c = i & 63;
    int h = row >> 5, k = row & 31;
    sm[SM_W4P + i] = 0.25f * W4[k * 256 + h * 64 + c];
  }
}

// ---- sort phase 1: per-block bucket histogram + fused ea dim-sum reduction
//      (the ea stream ALSO pre-warms L3 for k_pack's random gathers — keep!) ----
__global__ __launch_bounds__(1024) void k_hist1(const int* __restrict__ ei,
                                                const float* __restrict__ ea,
                                                int* __restrict__ blk_cnt,
                                                float* __restrict__ sm) {
  __shared__ int hist[NBUCK];
  __shared__ float lsum[16];
  int t = threadIdx.x;
  for (int i = t; i < NBUCK; i += 1024) hist[i] = 0;
  if (t < 16) lsum[t] = 0.f;
  __syncthreads();
  for (int e = blockIdx.x * 1024 + t; e < ETOT; e += NB1 * 1024) {
    int dst = (e < EE) ? ei[EE + e] : (e - EE);
    atomicAdd(&hist[dst >> 7], 1);
  }
  {
    const float4* ea4 = (const float4*)ea;
    int q = t & 3;
    float4 a = make_float4(0.f, 0.f, 0.f, 0.f);
    for (size_t i = (size_t)blockIdx.x * 1024 + t; i < (size_t)EE * 4;
         i += (size_t)NB1 * 1024) {
      float4 v = ea4[i];
      a.x += v.x; a.y += v.y; a.z += v.z; a.w += v.w;
    }
    for (int m = 4; m < 64; m <<= 1) {
      a.x += __shfl_xor(a.x, m, 64);
      a.y += __shfl_xor(a.y, m, 64);
      a.z += __shfl_xor(a.z, m, 64);
      a.w += __shfl_xor(a.w, m, 64);
    }
    if ((t & 63) < 4) {
      atomicAdd(&lsum[q * 4 + 0], a.x);
      atomicAdd(&lsum[q * 4 + 1], a.y);
      atomicAdd(&lsum[q * 4 + 2], a.z);
      atomicAdd(&lsum[q * 4 + 3], a.w);
    }
  }
  __syncthreads();
  for (int i = t; i < NBUCK; i += 1024) blk_cnt[blockIdx.x * NBUCK + i] = hist[i];
  if (t < 16) atomicAdd(&sm[SM_MEAN + t], lsum[t]);
}

// ---- scan A: per-bucket exclusive scan over the 256 blocks ----
__global__ __launch_bounds__(256) void k_bscan_a(const int* __restrict__ blk_cnt,
                                                 int* __restrict__ blk_base_T,
                                                 int* __restrict__ bucket_tot) {
  __shared__ int s[256];
  int b = blockIdx.x, t = threadIdx.x;
  int v = blk_cnt[t * NBUCK + b];
  s[t] = v;
  __syncthreads();
  for (int off = 1; off < 256; off <<= 1) {
    int x = (t >= off) ? s[t - off] : 0;
    __syncthreads();
    s[t] += x;
    __syncthreads();
  }
  blk_base_T[b * 256 + t] = s[t] - v;
  if (t == 255) bucket_tot[b] = s[255];
}

// ---- scan B: exclusive scan of bucket totals ----
__global__ __launch_bounds__(1024) void k_bscan_b(const int* __restrict__ bucket_tot,
                                                  int* __restrict__ bucket_base,
                                                  int* __restrict__ row_off) {
  __shared__ int s[1024];
  int t = threadIdx.x;
  int v = (t < NBUCK) ? bucket_tot[t] : 0;
  s[t] = v;
  __syncthreads();
  for (int off = 1; off < 1024; off <<= 1) {
    int x = (t >= off) ? s[t - off] : 0;
    __syncthreads();
    s[t] += x;
    __syncthreads();
  }
  if (t < NBUCK) bucket_base[t] = s[t] - v;
  if (t == 0) {
    bucket_base[NBUCK] = ETOT;
    row_off[NN] = ETOT;
  }
}

// ---- sort phase 1 scatter: packed (src, eid|dstlow) into dense bucket regions ----
__global__ __launch_bounds__(1024) void k_scatter1(const int* __restrict__ ei,
                                                   const int* __restrict__ bucket_base,
                                                   const int* __restrict__ blk_base_T,
                                                   uint2* __restrict__ pairs) {
  __shared__ int base[NBUCK];
  __shared__ int rank[NBUCK];
  int t = threadIdx.x, blk = blockIdx.x;
  for (int i = t; i < NBUCK; i += 1024) {
    base[i] = bucket_base[i] + blk_base_T[i * 256 + blk];
    rank[i] = 0;
  }
  __syncthreads();
  for (int e = blk * 1024 + t; e < ETOT; e += NB1 * 1024) {
    int src, dst;
    if (e < EE) {
      src = ei[e];
      dst = ei[EE + e];
    } else {
      src = dst = e - EE;
    }
    int bin = dst >> 7;
    int r = atomicAdd(&rank[bin], 1);
    pairs[base[bin] + r] =
        make_uint2((unsigned)src, (unsigned)e | ((unsigned)(dst & 127) << 21));
  }
}

// ---- sort phase 2 (lean): LDS exact sort, coalesced csr_src + eidx writes ----
__global__ __launch_bounds__(256) void k_sort2(const uint2* __restrict__ pairs,
                                               const int* __restrict__ bucket_base,
                                               int* __restrict__ row_off,
                                               int* __restrict__ csr_src,
                                               int* __restrict__ eidx) {
  __shared__ uint2 plds[CAP];
  __shared__ unsigned short perm[CAP];
  __shared__ int hist[128];
  __shared__ int scan[128];
  __shared__ int rankv[128];
  int b = blockIdx.x, t = threadIdx.x;
  int start = bucket_base[b], end = bucket_base[b + 1];
  int cnt = end - start;
  if (t < 128) hist[t] = 0;
  __syncthreads();
  bool fits = (cnt <= CAP);
  if (fits) {
    for (int i = t; i < cnt; i += 256) {
      uint2 pe = pairs[start + i];
      plds[i] = pe;
      atomicAdd(&hist[(pe.y >> 21) & 127], 1);
    }
  } else {
    for (int i = t; i < cnt; i += 256)
      atomicAdd(&hist[(pairs[start + i].y >> 21) & 127], 1);
  }
  __syncthreads();
  if (t < 128) scan[t] = hist[t];
  __syncthreads();
  for (int off = 1; off < 128; off <<= 1) {
    int x = (t >= off && t < 128) ? scan[t - off] : 0;
    __syncthreads();
    if (t < 128) scan[t] += x;
    __syncthreads();
  }
  if (t < 128) {
    int excl = scan[t] - hist[t];
    rankv[t] = excl;
    int dst = b * 128 + t;
    if (dst < NN) row_off[dst] = start + excl;
  }
  __syncthreads();
  if (fits) {
    for (int i = t; i < cnt; i += 256) {
      int bin = (plds[i].y >> 21) & 127;
      int r = atomicAdd(&rankv[bin], 1);
      perm[r] = (unsigned short)i;
    }
    __syncthreads();
    for (int r = t; r < cnt; r += 256) {
      uint2 pe = plds[perm[r]];
      csr_src[start + r] = (int)pe.x;
      eidx[start + r] = (int)(pe.y & 0x1fffffu);
    }
  } else {
    for (int i = t; i < cnt; i += 256) {
      uint2 pe = pairs[start + i];
      int bin = (pe.y >> 21) & 127;
      int r = atomicAdd(&rankv[bin], 1);
      csr_src[start + r] = (int)pe.x;
      eidx[start + r] = (int)(pe.y & 0x1fffffu);
    }
  }
}

// ---- pack GEMV in CSR order: random 64B ea gather (L3-warm), coalesced writes ----
__global__ __launch_bounds__(256) void k_pack(const int* __restrict__ eidx,
                                              const float* __restrict__ ea,
                                              const float* __restrict__ sm,
                                              ull* __restrict__ apc) {
  __shared__ float sWea[256];
  __shared__ float smean[16];
  int t = threadIdx.x;
  sWea[t] = sm[SM_WEA + t];
  if (t < 16) smean[t] = sm[SM_MEAN + t] * (1.f / EE);
  __syncthreads();
  int pos = blockIdx.x * 256 + t;
  if (pos >= ETOT) return;
  int eid = eidx[pos];
  float eav[16];
  if (eid < EE) {
    const float4* p = (const float4*)(ea + (size_t)eid * 16);
    float4 v0 = p[0], v1 = p[1], v2 = p[2], v3 = p[3];
    eav[0] = v0.x; eav[1] = v0.y; eav[2] = v0.z; eav[3] = v0.w;
    eav[4] = v1.x; eav[5] = v1.y; eav[6] = v1.z; eav[7] = v1.w;
    eav[8] = v2.x; eav[9] = v2.y; eav[10] = v2.z; eav[11] = v2.w;
    eav[12] = v3.x; eav[13] = v3.y; eav[14] = v3.z; eav[15] = v3.w;
  } else {
#pragma unroll
    for (int d = 0; d < 16; d++) eav[d] = smean[d];
  }
#pragma unroll
  for (int l = 0; l < 4; l++) {
    ull pk = 0;
#pragma unroll
    for (int h = 0; h < 4; h++) {
      float s = 0.f;
#pragma unroll
      for (int d = 0; d < 16; d++) s += eav[d] * sWea[l * 64 + d * 4 + h];
      pk |= (ull)f2bf(s) << (16 * h);
    }
    apc[(size_t)l * ETOT + pos] = pk;
  }
}

// ---- layer-1 node transform: hx = x@W1 (bf16 out), alpha reductions ----
template <int DIN>
__global__ __launch_bounds__(256) void k_t(const float* __restrict__ in,
                                           const float* __restrict__ W,
                                           const float* __restrict__ a_s,
                                           const float* __restrict__ a_d,
                                           unsigned short* __restrict__ hxb,
                                           float* __restrict__ ssrc,
                                           float* __restrict__ sdst) {
  __shared__ float4 sW[DIN * 8];
  __shared__ float sas[32], sad[32];
  int t = threadIdx.x;
  for (int i = t; i < DIN * 8; i += 256) sW[i] = ((const float4*)W)[i];
  if (t < 32) { sas[t] = a_s[t]; sad[t] = a_d[t]; }
  __syncthreads();
  int n = blockIdx.x * 256 + t;
  if (n >= NN) return;
  float acc[32];
#pragma unroll
  for (int j = 0; j < 32; j++) acc[j] = 0.f;
  const float* xr = in + (size_t)n * DIN;
  for (int k = 0; k < DIN; k += 4) {
    float4 xv = *(const float4*)(xr + k);
    float xa[4] = {xv.x, xv.y, xv.z, xv.w};
#pragma unroll
    for (int kk = 0; kk < 4; kk++) {
#pragma unroll
      for (int j4 = 0; j4 < 8; j4++) {
        float4 ww = sW[(k + kk) * 8 + j4];
        acc[j4 * 4 + 0] += xa[kk] * ww.x;
        acc[j4 * 4 + 1] += xa[kk] * ww.y;
        acc[j4 * 4 + 2] += xa[kk] * ww.z;
        acc[j4 * 4 + 3] += xa[kk] * ww.w;
      }
    }
  }
  float ssum[4], dsum[4];
#pragma unroll
  for (int h = 0; h < 4; h++) {
    float s = 0.f, d = 0.f;
#pragma unroll
    for (int c = 0; c < 8; c++) {
      s += acc[h * 8 + c] * sas[h * 8 + c];
      d += acc[h * 8 + c] * sad[h * 8 + c];
    }
    ssum[h] = s;
    dsum[h] = d;
  }
  unsigned int up[16];
#pragma unroll
  for (int i = 0; i < 16; i++)
    up[i] = (unsigned)f2bf(acc[2 * i]) | ((unsigned)f2bf(acc[2 * i + 1]) << 16);
  uint4* ho = (uint4*)(hxb + (size_t)n * 32);
  ho[0] = make_uint4(up[0], up[1], up[2], up[3]);
  ho[1] = make_uint4(up[4], up[5], up[6], up[7]);
  ho[2] = make_uint4(up[8], up[9], up[10], up[11]);
  ho[3] = make_uint4(up[12], up[13], up[14], up[15]);
  ((float4*)ssrc)[n] = make_float4(ssum[0], ssum[1], ssum[2], ssum[3]);
  ((float4*)sdst)[n] = make_float4(dsum[0], dsum[1], dsum[2], dsum[3]);
}

// ---- fused aggregation (layers 1,2): agg + bias + lrelu + in-register 32x32
//      transform via shfl + next-layer alpha reductions + bf16 feature write ----
__global__ __launch_bounds__(256) void k_aggt(const int* __restrict__ row_off,
                                              const int* __restrict__ csr_src,
                                              const ull* __restrict__ apl,
                                              const unsigned short* __restrict__ hxb,
                                              const float* __restrict__ ssrc,
                                              const float* __restrict__ sdst,
                                              const float* __restrict__ bias,
                                              const float* __restrict__ Wn,
                                              const float* __restrict__ asn,
                                              const float* __restrict__ adn,
                                              unsigned short* __restrict__ hxb_out,
                                              float* __restrict__ ssrc_out,
                                              float* __restrict__ sdst_out) {
  __shared__ float4 sW[256];  // Wn [32][32] as float4
  __shared__ float sas[32], sad[32];
  int t = threadIdx.x;
  sW[t] = ((const float4*)Wn)[t];
  if (t < 32) { sas[t] = asn[t]; sad[t] = adn[t]; }
  __syncthreads();
  int g = t >> 3, j = t & 7, h = j >> 1;
  int n = blockIdx.x * 32 + g;
  float sd = sdst[n * 4 + h];
  int e0 = row_off[n], e1 = row_off[n + 1];
  float den = 0.f;
  float4 acc = make_float4(0.f, 0.f, 0.f, 0.f);
  int e = e0;
  for (; e + 8 <= e1; e += 8) {
    int s[8];
    ull p[8];
#pragma unroll
    for (int k = 0; k < 8; k++) s[k] = csr_src[e + k];
#pragma unroll
    for (int k = 0; k < 8; k++) p[k] = apl[e + k];
    float a[8];
    uint2 u[8];
#pragma unroll
    for (int k = 0; k < 8; k++) a[k] = ssrc[s[k] * 4 + h];
#pragma unroll
    for (int k = 0; k < 8; k++)
      u[k] = *(const uint2*)(hxb + (size_t)s[k] * 32 + (j << 2));
#pragma unroll
    for (int k = 0; k < 8; k++) {
      float al = a[k] + sd + bf2f((unsigned)(unsigned short)(p[k] >> (16 * h)));
      float q = __expf(fminf(lrelu(al, 0.2f), 80.f));
      den += q;
      acc.x += q * bf2f(u[k].x & 0xffffu);
      acc.y += q * bf2f(u[k].x >> 16);
      acc.z += q * bf2f(u[k].y & 0xffffu);
      acc.w += q * bf2f(u[k].y >> 16);
    }
  }
  for (; e + 4 <= e1; e += 4) {
    int s[4];
    ull p[4];
#pragma unroll
    for (int k = 0; k < 4; k++) s[k] = csr_src[e + k];
#pragma unroll
    for (int k = 0; k < 4; k++) p[k] = apl[e + k];
    float a[4];
    uint2 u[4];
#pragma unroll
    for (int k = 0; k < 4; k++) a[k] = ssrc[s[k] * 4 + h];
#pragma unroll
    for (int k = 0; k < 4; k++)
      u[k] = *(const uint2*)(hxb + (size_t)s[k] * 32 + (j << 2));
#pragma unroll
    for (int k = 0; k < 4; k++) {
      float al = a[k] + sd + bf2f((unsigned)(unsigned short)(p[k] >> (16 * h)));
      float q = __expf(fminf(lrelu(al, 0.2f), 80.f));
      den += q;
      acc.x += q * bf2f(u[k].x & 0xffffu);
      acc.y += q * bf2f(u[k].x >> 16);
      acc.z += q * bf2f(u[k].y & 0xffffu);
      acc.w += q * bf2f(u[k].y >> 16);
    }
  }
  for (; e < e1; ++e) {
    int src = csr_src[e];
    ull pk = apl[e];
    float al = ssrc[src * 4 + h] + sd + bf2f((unsigned)(unsigned short)(pk >> (16 * h)));
    al = fminf(lrelu(al, 0.2f), 80.f);
    uint2 u = *(const uint2*)(hxb + (size_t)src * 32 + (j << 2));
    float p = __expf(al);
    den += p;
    acc.x += p * bf2f(u.x & 0xffffu);
    acc.y += p * bf2f(u.x >> 16);
    acc.z += p * bf2f(u.y & 0xffffu);
    acc.w += p * bf2f(u.y >> 16);
  }
  float inv = 1.f / (den + 1e-16f);
  float4 b = *(const float4*)(bias + (j << 2));
  float i0 = lrelu(acc.x * inv + b.x, 0.01f);
  float i1 = lrelu(acc.y * inv + b.y, 0.01f);
  float i2 = lrelu(acc.z * inv + b.z, 0.01f);
  float i3 = lrelu(acc.w * inv + b.w, 0.01f);
  // in-register transform: next_hx[j*4..+3] = sum_i in[i] * Wn[i][j*4..+3]
  int gbase = (t & 63) & ~7;
  float n0 = 0.f, n1 = 0.f, n2 = 0.f, n3 = 0.f;
#pragma unroll
  for (int k = 0; k < 8; k++) {
    int sl = gbase + k;
    float v0 = __shfl(i0, sl, 64);
    float v1 = __shfl(i1, sl, 64);
    float v2 = __shfl(i2, sl, 64);
    float v3 = __shfl(i3, sl, 64);
    float4 w0 = sW[(k * 4 + 0) * 8 + j];
    n0 += v0 * w0.x; n1 += v0 * w0.y; n2 += v0 * w0.z; n3 += v0 * w0.w;
    float4 w1 = sW[(k * 4 + 1) * 8 + j];
    n0 += v1 * w1.x; n1 += v1 * w1.y; n2 += v1 * w1.z; n3 += v1 * w1.w;
    float4 w2 = sW[(k * 4 + 2) * 8 + j];
    n0 += v2 * w2.x; n1 += v2 * w2.y; n2 += v2 * w2.z; n3 += v2 * w2.w;
    float4 w3 = sW[(k * 4 + 3) * 8 + j];
    n0 += v3 * w3.x; n1 += v3 * w3.y; n2 += v3 * w3.z; n3 += v3 * w3.w;
  }
  // next-layer attention reductions: lane's 4 dims all in head j>>1
  float ps = n0 * sas[j * 4 + 0] + n1 * sas[j * 4 + 1] + n2 * sas[j * 4 + 2] +
             n3 * sas[j * 4 + 3];
  float pd = n0 * sad[j * 4 + 0] + n1 * sad[j * 4 + 1] + n2 * sad[j * 4 + 2] +
             n3 * sad[j * 4 + 3];
  ps += __shfl_xor(ps, 1, 64);
  pd += __shfl_xor(pd, 1, 64);
  if ((j & 1) == 0) {
    ssrc_out[n * 4 + (j >> 1)] = ps;
    sdst_out[n * 4 + (j >> 1)] = pd;
  }
  unsigned u0 = (unsigned)f2bf(n0) | ((unsigned)f2bf(n1) << 16);
  unsigned u1 = (unsigned)f2bf(n2) | ((unsigned)f2bf(n3) << 16);
  *(uint2*)(hxb_out + (size_t)n * 32 + (j << 2)) = make_uint2(u0, u1);
}

// ---- fused aggregation (layer 3): agg + bias + lrelu + Vs4/Vd4 reductions
//      + bf16 h3 write ----
__global__ __launch_bounds__(256) void k_aggt3(const int* __restrict__ row_off,
                                               const int* __restrict__ csr_src,
                                               const ull* __restrict__ apl,
                                               const unsigned short* __restrict__ hxb,
                                               const float* __restrict__ ssrc,
                                               const float* __restrict__ sdst,
                                               const float* __restrict__ bias,
                                               const float* __restrict__ sm,
                                               unsigned short* __restrict__ h3b,
                                               float* __restrict__ ssrc4,
                                               float* __restrict__ sdst4) {
  __shared__ float sVs[128], sVd[128];
  int t = threadIdx.x;
  if (t < 128) { sVs[t] = sm[SM_VS4 + t]; sVd[t] = sm[SM_VD4 + t]; }
  __syncthreads();
  int g = t >> 3, j = t & 7, h = j >> 1;
  int n = blockIdx.x * 32 + g;
  float sd = sdst[n * 4 + h];
  int e0 = row_off[n], e1 = row_off[n + 1];
  float den = 0.f;
  float4 acc = make_float4(0.f, 0.f, 0.f, 0.f);
  int e = e0;
  for (; e + 8 <= e1; e += 8) {
    int s[8];
    ull p[8];
#pragma unroll
    for (int k = 0; k < 8; k++) s[k] = csr_src[e + k];
#pragma unroll
    for (int k = 0; k < 8; k++) p[k] = apl[e + k];
    float a[8];
    uint2 u[8];
#pragma unroll
    for (int k = 0; k < 8; k++) a[k] = ssrc[s[k] * 4 + h];
#pragma unroll
    for (int k = 0; k < 8; k++)
      u[k] = *(const uint2*)(hxb + (size_t)s[k] * 32 + (j << 2));
#pragma unroll
    for (int k = 0; k < 8; k++) {
      float al = a[k] + sd + bf2f((unsigned)(unsigned short)(p[k] >> (16 * h)));
      float q = __expf(fminf(lrelu(al, 0.2f), 80.f));
      den += q;
      acc.x += q * bf2f(u[k].x & 0xffffu);
      acc.y += q * bf2f(u[k].x >> 16);
      acc.z += q * bf2f(u[k].y & 0xffffu);
      acc.w += q * bf2f(u[k].y >> 16);
    }
  }
  for (; e + 4 <= e1; e += 4) {
    int s[4];
    ull p[4];
#pragma unroll
    for (int k = 0; k < 4; k++) s[k] = csr_src[e + k];
#pragma unroll
    for (int k = 0; k < 4; k++) p[k] = apl[e + k];
    float a[4];
    uint2 u[4];
#pragma unroll
    for (int k = 0; k < 4; k++) a[k] = ssrc[s[k] * 4 + h];
#pragma unroll
    for (int k = 0; k < 4; k++)
      u[k] = *(const uint2*)(hxb + (size_t)s[k] * 32 + (j << 2));
#pragma unroll
    for (int k = 0; k < 4; k++) {
      float al = a[k] + sd + bf2f((unsigned)(unsigned short)(p[k] >> (16 * h)));
      float q = __expf(fminf(lrelu(al, 0.2f), 80.f));
      den += q;
      acc.x += q * bf2f(u[k].x & 0xffffu);
      acc.y += q * bf2f(u[k].x >> 16);
      acc.z += q * bf2f(u[k].y & 0xffffu);
      acc.w += q * bf2f(u[k].y >> 16);
    }
  }
  for (; e < e1; ++e) {
    int src = csr_src[e];
    ull pk = apl[e];
    float al = ssrc[src * 4 + h] + sd + bf2f((unsigned)(unsigned short)(pk >> (16 * h)));
    al = fminf(lrelu(al, 0.2f), 80.f);
    uint2 u = *(const uint2*)(hxb + (size_t)src * 32 + (j << 2));
    float p = __expf(al);
    den += p;
    acc.x += p * bf2f(u.x & 0xffffu);
    acc.y += p * bf2f(u.x >> 16);
    acc.z += p * bf2f(u.y & 0xffffu);
    acc.w += p * bf2f(u.y >> 16);
  }
  float inv = 1.f / (den + 1e-16f);
  float4 b = *(const float4*)(bias + (j << 2));
  float o0 = lrelu(acc.x * inv + b.x, 0.01f);
  float o1 = lrelu(acc.y * inv + b.y, 0.01f);
  float o2 = lrelu(acc.z * inv + b.z, 0.01f);
  float o3 = lrelu(acc.w * inv + b.w, 0.01f);
  // Vs4/Vd4 reductions: ssum4[hh] = sum_k h3[k] * Vs4[k][hh]
  float ps0 = o0 * sVs[(j * 4 + 0) * 4 + 0] + o1 * sVs[(j * 4 + 1) * 4 + 0] +
              o2 * sVs[(j * 4 + 2) * 4 + 0] + o3 * sVs[(j * 4 + 3) * 4 + 0];
  float ps1 = o0 * sVs[(j * 4 + 0) * 4 + 1] + o1 * sVs[(j * 4 + 1) * 4 + 1] +
              o2 * sVs[(j * 4 + 2) * 4 + 1] + o3 * sVs[(j * 4 + 3) * 4 + 1];
  float ps2 = o0 * sVs[(j * 4 + 0) * 4 + 2] + o1 * sVs[(j * 4 + 1) * 4 + 2] +
              o2 * sVs[(j * 4 + 2) * 4 + 2] + o3 * sVs[(j * 4 + 3) * 4 + 2];
  float ps3 = o0 * sVs[(j * 4 + 0) * 4 + 3] + o1 * sVs[(j * 4 + 1) * 4 + 3] +
              o2 * sVs[(j * 4 + 2) * 4 + 3] + o3 * sVs[(j * 4 + 3) * 4 + 3];
  float pd0 = o0 * sVd[(j * 4 + 0) * 4 + 0] + o1 * sVd[(j * 4 + 1) * 4 + 0] +
              o2 * sVd[(j * 4 + 2) * 4 + 0] + o3 * sVd[(j * 4 + 3) * 4 + 0];
  float pd1 = o0 * sVd[(j * 4 + 0) * 4 + 1] + o1 * sVd[(j * 4 + 1) * 4 + 1] +
              o2 * sVd[(j * 4 + 2) * 4 + 1] + o3 * sVd[(j * 4 + 3) * 4 + 1];
  float pd2 = o0 * sVd[(j * 4 + 0) * 4 + 2] + o1 * sVd[(j * 4 + 1) * 4 + 2] +
              o2 * sVd[(j * 4 + 2) * 4 + 2] + o3 * sVd[(j * 4 + 3) * 4 + 2];
  float pd3 = o0 * sVd[(j * 4 + 0) * 4 + 3] + o1 * sVd[(j * 4 + 1) * 4 + 3] +
              o2 * sVd[(j * 4 + 2) * 4 + 3] + o3 * sVd[(j * 4 + 3) * 4 + 3];
#pragma unroll
  for (int m = 1; m < 8; m <<= 1) {
    ps0 += __shfl_xor(ps0, m, 64);
    ps1 += __shfl_xor(ps1, m, 64);
    ps2 += __shfl_xor(ps2, m, 64);
    ps3 += __shfl_xor(ps3, m, 64);
    pd0 += __shfl_xor(pd0, m, 64);
    pd1 += __shfl_xor(pd1, m, 64);
    pd2 += __shfl_xor(pd2, m, 64);
    pd3 += __shfl_xor(pd3, m, 64);
  }
  if (j == 0) {
    ((float4*)ssrc4)[n] = make_float4(ps0, ps1, ps2, ps3);
    ((float4*)sdst4)[n] = make_float4(pd0, pd1, pd2, pd3);
  }
  unsigned u0 = (unsigned)f2bf(o0) | ((unsigned)f2bf(o1) << 16);
  unsigned u1 = (unsigned)f2bf(o2) | ((unsigned)f2bf(o3) << 16);
  *(uint2*)(h3b + (size_t)n * 32 + (j << 2)) = make_uint2(u0, u1);
}

// ---- layer-4 aggregation: aggregate h3 per head, no-max softmax, 8x batched ----
__global__ __launch_bounds__(256) void k_agg4(const int* __restrict__ row_off,
                                              const int* __restrict__ csr_src,
                                              const ull* __restrict__ apl,
                                              const unsigned short* __restrict__ h3b,
                                              const float* __restrict__ ssrc,
                                              const float* __restrict__ sdst,
                                              unsigned short* __restrict__ aggb) {
  int t = threadIdx.x;
  int g = t >> 3, j = t & 7;
  int n = blockIdx.x * 32 + g;
  if (n >= NN) return;
  float4 sdv = ((const float4*)sdst)[n];
  float sda[4] = {sdv.x, sdv.y, sdv.z, sdv.w};
  int e0 = row_off[n], e1 = row_off[n + 1];
  float den[4];
  float4 acc[4];
#pragma unroll
  for (int h = 0; h < 4; h++) {
    den[h] = 0.f;
    acc[h] = make_float4(0.f, 0.f, 0.f, 0.f);
  }
  int e = e0;
  for (; e + 8 <= e1; e += 8) {
    int s[8];
    ull p[8];
#pragma unroll
    for (int k = 0; k < 8; k++) s[k] = csr_src[e + k];
#pragma unroll
    for (int k = 0; k < 8; k++) p[k] = apl[e + k];
    float4 sv[8];
    uint2 u[8];
#pragma unroll
    for (int k = 0; k < 8; k++) sv[k] = ((const float4*)ssrc)[s[k]];
#pragma unroll
    for (int k = 0; k < 8; k++)
      u[k] = *(const uint2*)(h3b + (size_t)s[k] * 32 + (j << 2));
#pragma unroll
    for (int k = 0; k < 8; k++) {
      float x0 = bf2f(u[k].x & 0xffffu), x1 = bf2f(u[k].x >> 16);
      float x2 = bf2f(u[k].y & 0xffffu), x3 = bf2f(u[k].y >> 16);
      float sa[4] = {sv[k].x, sv[k].y, sv[k].z, sv[k].w};
#pragma unroll
      for (int h = 0; h < 4; h++) {
        float al = sa[h] + sda[h] + bf2f((unsigned)(unsigned short)(p[k] >> (16 * h)));
        float q = __expf(fminf(lrelu(al, 0.2f), 80.f));
        den[h] += q;
        acc[h].x += q * x0;
        acc[h].y += q * x1;
        acc[h].z += q * x2;
        acc[h].w += q * x3;
      }
    }
  }
  for (; e + 4 <= e1; e += 4) {
    int s[4];
    ull p[4];
#pragma unroll
    for (int k = 0; k < 4; k++) s[k] = csr_src[e + k];
#pragma unroll
    for (int k = 0; k < 4; k++) p[k] = apl[e + k];
    float4 sv[4];
    uint2 u[4];
#pragma unroll
    for (int k = 0; k < 4; k++) sv[k] = ((const float4*)ssrc)[s[k]];
#pragma unroll
    for (int k = 0; k < 4; k++)
      u[k] = *(const uint2*)(h3b + (size_t)s[k] * 32 + (j << 2));
#pragma unroll
    for (int k = 0; k < 4; k++) {
      float x0 = bf2f(u[k].x & 0xffffu), x1 = bf2f(u[k].x >> 16);
      float x2 = bf2f(u[k].y & 0xffffu), x3 = bf2f(u[k].y >> 16);
      float sa[4] = {sv[k].x, sv[k].y, sv[k].z, sv[k].w};
#pragma unroll
      for (int h = 0; h < 4; h++) {
        float al = sa[h] + sda[h] + bf2f((unsigned)(unsigned short)(p[k] >> (16 * h)));
        float q = __expf(fminf(lrelu(al, 0.2f), 80.f));
        den[h] += q;
        acc[h].x += q * x0;
        acc[h].y += q * x1;
        acc[h].z += q * x2;
        acc[h].w += q * x3;
      }
    }
  }
  for (; e < e1; ++e) {
    int src = csr_src[e];
    ull pk = apl[e];
    float4 ssv = ((const float4*)ssrc)[src];
    float ssa[4] = {ssv.x, ssv.y, ssv.z, ssv.w};
    uint2 u = *(const uint2*)(h3b + (size_t)src * 32 + (j << 2));
    float hx0 = bf2f(u.x & 0xffffu), hx1 = bf2f(u.x >> 16);
    float hx2 = bf2f(u.y & 0xffffu), hx3 = bf2f(u.y >> 16);
#pragma unroll
    for (int h = 0; h < 4; h++) {
      float al = ssa[h] + sda[h] + bf2f((unsigned)(unsigned short)(pk >> (16 * h)));
      al = fminf(lrelu(al, 0.2f), 80.f);
      float p = __expf(al);
      den[h] += p;
      acc[h].x += p * hx0;
      acc[h].y += p * hx1;
      acc[h].z += p * hx2;
      acc[h].w += p * hx3;
    }
  }
#pragma unroll
  for (int h = 0; h < 4; h++) {
    float inv = 1.f / (den[h] + 1e-16f);
    unsigned int u0 = (unsigned)f2bf(acc[h].x * inv) | ((unsigned)f2bf(acc[h].y * inv) << 16);
    unsigned int u1 = (unsigned)f2bf(acc[h].z * inv) | ((unsigned)f2bf(acc[h].w * inv) << 16);
    *(uint2*)(aggb + (size_t)n * 128 + h * 32 + (j << 2)) = make_uint2(u0, u1);
  }
}

// ---- layer-4 epilogue: [N,128](bf16) @ W4p[128,64] + b4, lrelu -> h4 ----
__global__ __launch_bounds__(256) void k_epi4(const unsigned short* __restrict__ aggb,
                                              const float* __restrict__ sm,
                                              const float* __restrict__ b4,
                                              float* __restrict__ h4) {
  __shared__ float4 sW[2048];
  __shared__ float sb[64];
  int t = threadIdx.x;
  for (int i = t; i < 2048; i += 256) sW[i] = ((const float4*)(sm + SM_W4P))[i];
  if (t < 64) sb[t] = b4[t];
  __syncthreads();
  int n = blockIdx.x * 256 + t;
  if (n >= NN) return;
  float acc[64];
#pragma unroll
  for (int j = 0; j < 64; j++) acc[j] = 0.f;
  const unsigned short* r = aggb + (size_t)n * 128;
  for (int k = 0; k < 128; k += 4) {
    uint2 u = *(const uint2*)(r + k);
    float va[4] = {bf2f(u.x & 0xffffu), bf2f(u.x >> 16), bf2f(u.y & 0xffffu),
                   bf2f(u.y >> 16)};
#pragma unroll
    for (int kk = 0; kk < 4; kk++) {
#pragma unroll
      for (int j4 = 0; j4 < 16; j4++) {
        float4 wv = sW[(k + kk) * 16 + j4];
        acc[j4 * 4 + 0] += va[kk] * wv.x;
        acc[j4 * 4 + 1] += va[kk] * wv.y;
        acc[j4 * 4 + 2] += va[kk] * wv.z;
        acc[j4 * 4 + 3] += va[kk] * wv.w;
      }
    }
  }
  float* o = h4 + (size_t)n * 64;
#pragma unroll
  for (int j4 = 0; j4 < 16; j4++) {
    float4 ov;
    ov.x = lrelu(acc[j4 * 4 + 0] + sb[j4 * 4 + 0], 0.01f);
    ov.y = lrelu(acc[j4 * 4 + 1] + sb[j4 * 4 + 1], 0.01f);
    ov.z = lrelu(acc[j4 * 4 + 2] + sb[j4 * 4 + 2], 0.01f);
    ov.w = lrelu(acc[j4 * 4 + 3] + sb[j4 * 4 + 3], 0.01f);
    ((float4*)o)[j4] = ov;
  }
}

// ---- pooling (lane c of a wave covers channel c of one node: coalesced atomics) ----
__global__ __launch_bounds__(256) void k_pool1(const float* __restrict__ h4,
                                               const int* __restrict__ sidx,
                                               float* __restrict__ pool1) {
  int i = blockIdx.x * 256 + threadIdx.x;
  if (i >= NN * 64) return;
  int n = i >> 6, c = i & 63;
  atomicAdd(&pool1[(size_t)sidx[n] * 64 + c], h4[i]);
}

__global__ __launch_bounds__(256) void k_pool2(const float* __restrict__ pool1,
                                               const float* __restrict__ snorm,
                                               const int* __restrict__ nodes,
                                               float* __restrict__ pool2) {
  int i = blockIdx.x * 256 + threadIdx.x;
  if (i >= MM * 64) return;
  int mi = i >> 6, c = i & 63;
  float v = pool1[i] / snorm[mi];
  atomicAdd(&pool2[(size_t)nodes[mi] * 64 + c], v);
}

// ---- final head: one wave per group ----
__global__ __launch_bounds__(64) void k_final(const float* __restrict__ pool2,
                                              const float* __restrict__ h4,
                                              const int* __restrict__ dvi,
                                              const float* __restrict__ Wp,
                                              const float* __restrict__ Wt,
                                              const float* __restrict__ Wo,
                                              const float* __restrict__ bo,
                                              float* __restrict__ out) {
  __shared__ float p[64], tt[64];
  int gI = blockIdx.x, j = threadIdx.x;
  p[j] = pool2[gI * 64 + j];
  tt[j] = h4[(size_t)dvi[gI] * 64 + j];
  __syncthreads();
  float f1 = 0.f, f2 = 0.f;
#pragma unroll 8
  for (int c = 0; c < 64; c++) {
    f1 += p[c] * Wp[c * 64 + j];
    f2 += tt[c] * Wt[c * 64 + j];
  }
  f1 = lrelu(f1, 0.01f);
  f2 = lrelu(f2, 0.01f);
  float v = f1 * Wo[j] + f2 * Wo[64 + j];
  for (int off = 32; off > 0; off >>= 1) v += __shfl_down(v, off, 64);
  if (j == 0) out[gI] = v + bo[0];
}

extern "C" void kernel_launch(void* const* d_in, const int* in_sizes, int n_in,
                              void* d_out, int out_size, void* d_ws, size_t ws_size,
                              hipStream_t stream) {
  const float* x = (const float*)d_in[0];
  const int* ei = (const int*)d_in[1];
  const float* ea = (const float*)d_in[2];
  const int* sidx = (const int*)d_in[3];
  const float* snorm = (const float*)d_in[4];
  const int* nodes = (const int*)d_in[5];
  const int* dvi = (const int*)d_in[6];
  const float* W1 = (const float*)d_in[7];
  const float* as1 = (const float*)d_in[9];
  const float* ad1 = (const float*)d_in[10];
  const float* b1 = (const float*)d_in[12];
  const float* W2 = (const float*)d_in[13];
  const float* as2 = (const float*)d_in[15];
  const float* ad2 = (const float*)d_in[16];
  const float* b2 = (const float*)d_in[18];
  const float* W3 = (const float*)d_in[19];
  const float* as3 = (const float*)d_in[21];
  const float* ad3 = (const float*)d_in[22];
  const float* b3 = (const float*)d_in[24];
  const float* b4 = (const float*)d_in[30];
  const float* Wp = (const float*)d_in[31];
  const float* Wt = (const float*)d_in[32];
  const float* Wo = (const float*)d_in[33];
  const float* bo = (const float*)d_in[34];
  float* out = (float*)d_out;

  char* w = (char*)d_ws;
  size_t off = 0;
  auto take = [&](size_t bytes) -> char* {
    char* p = w + off;
    off = (off + bytes + 255) & ~(size_t)255;
    return p;
  };
  int* row_off = (int*)take((size_t)(NN + 1) * 4);
  float* sm = (float*)take(SM_TOTAL * 4);
  uint2* pairs = (uint2*)take((size_t)ETOT * 8);
  int* csr_src = (int*)take((size_t)ETOT * 4);
  int* eidx = (int*)take((size_t)ETOT * 4);
  ull* apc = (ull*)take((size_t)ETOT * 4 * 8);
  int* blk_cnt = (int*)take((size_t)NB1 * NBUCK * 4);
  int* blk_base_T = (int*)take((size_t)NBUCK * NB1 * 4);
  int* bucket_tot = (int*)take((size_t)NBUCK * 4);
  int* bucket_base = (int*)take((size_t)(NBUCK + 1) * 4);
  float* h4 = (float*)take((size_t)NN * 64 * 4);
  unsigned short* aggb = (unsigned short*)take((size_t)NN * 128 * 2);
  unsigned short* hxbA = (unsigned short*)take((size_t)NN * 32 * 2);
  unsigned short* hxbB = (unsigned short*)take((size_t)NN * 32 * 2);
  unsigned short* h3b = (unsigned short*)take((size_t)NN * 32 * 2);
  float* ssrcA = (float*)take((size_t)NN * 4 * 4);
  float* sdstA = (float*)take((size_t)NN * 4 * 4);
  float* ssrcB = (float*)take((size_t)NN * 4 * 4);
  float* sdstB = (float*)take((size_t)NN * 4 * 4);
  float* ssrc4 = (float*)take((size_t)NN * 4 * 4);
  float* sdst4 = (float*)take((size_t)NN * 4 * 4);
  float* pool1 = (float*)take((size_t)MM * 64 * 4);
  float* pool2 = (float*)take((size_t)GG * 64 * 4);
  if (off > ws_size) return;  // workspace too small -> visible validation failure

  hipMemsetAsync(sm, 0, 64, stream);
  hipMemsetAsync(pool1, 0, (size_t)MM * 64 * 4, stream);
  hipMemsetAsync(pool2, 0, (size_t)GG * 64 * 4, stream);

  k_pre<<<1, 256, 0, stream>>>(sm, (const float*)d_in[8], (const float*)d_in[14],
                               (const float*)d_in[20], (const float*)d_in[26],
                               (const float*)d_in[11], (const float*)d_in[17],
                               (const float*)d_in[23], (const float*)d_in[29],
                               (const float*)d_in[27], (const float*)d_in[28],
                               (const float*)d_in[25]);

  // counting sort by dst (two-level, no global atomics); ea-mean fused in hist1
  k_hist1<<<NB1, 1024, 0, stream>>>(ei, ea, blk_cnt, sm);
  k_bscan_a<<<NBUCK, 256, 0, stream>>>(blk_cnt, blk_base_T, bucket_tot);
  k_bscan_b<<<1, 1024, 0, stream>>>(bucket_tot, bucket_base, row_off);
  k_scatter1<<<NB1, 1024, 0, stream>>>(ei, bucket_base, blk_base_T, pairs);
  k_sort2<<<NBUCK, 256, 0, stream>>>(pairs, bucket_base, row_off, csr_src, eidx);
  k_pack<<<NB_E256, 256, 0, stream>>>(eidx, ea, sm, apc);

  // layer 1 transform, then fused agg+transform chain
  k_t<64><<<NB_N256, 256, 0, stream>>>(x, W1, as1, ad1, hxbA, ssrcA, sdstA);
  k_aggt<<<NB_AGG, 256, 0, stream>>>(row_off, csr_src, apc, hxbA, ssrcA, sdstA, b1, W2,
                                     as2, ad2, hxbB, ssrcB, sdstB);
  k_aggt<<<NB_AGG, 256, 0, stream>>>(row_off, csr_src, apc + (size_t)ETOT, hxbB, ssrcB,
                                     sdstB, b2, W3, as3, ad3, hxbA, ssrcA, sdstA);
  k_aggt3<<<NB_AGG, 256, 0, stream>>>(row_off, csr_src, apc + 2 * (size_t)ETOT, hxbA,
                                      ssrcA, sdstA, b3, sm, h3b, ssrc4, sdst4);
  k_agg4<<<NB_AGG, 256, 0, stream>>>(row_off, csr_src, apc + 3 * (size_t)ETOT, h3b,
                                     ssrc4, sdst4, aggb);
  k_epi4<<<NB_N256, 256, 0, stream>>>(aggb, sm, b4, h4);

  // pooling head
  k_pool1<<<(NN * 64) / 256, 256, 0, stream>>>(h4, sidx, pool1);
  k_pool2<<<(MM * 64) / 256, 256, 0, stream>>>(pool1, snorm, nodes, pool2);
  k_final<<<GG, 64, 0, stream>>>(pool2, h4, dvi, Wp, Wt, Wo, bo, out);
}